// Round 2
// baseline (1115.095 us; speedup 1.0000x reference)
//
#include <hip/hip_runtime.h>
#include <hip/hip_bf16.h>

#define N_NODES 524288
#define NUM_G   8192
#define HDIM    256

typedef short v8s __attribute__((ext_vector_type(8)));
typedef float v4f __attribute__((ext_vector_type(4)));
using bf16 = __hip_bfloat16;

// fp32 -> bf16 (round-to-nearest-even), bit-level (no NaN inputs expected)
static __device__ __forceinline__ unsigned short f2b(float f) {
    unsigned u = __builtin_bit_cast(unsigned, f);
    u += 0x7FFFu + ((u >> 16) & 1u);
    return (unsigned short)(u >> 16);
}
static __device__ __forceinline__ float b2f(unsigned short s) {
    unsigned u = ((unsigned)s) << 16;
    return __builtin_bit_cast(float, u);
}

// ---------------- weight pre-swizzle (fp32 -> bf16 MFMA B-fragment order) ----------------
// out[((ks*NT + nt)*64 + lane)*8 + j] = bf16(W[(ks*32 + (lane>>4)*8 + j)][nt*16 + (lane&15)])
__global__ __launch_bounds__(256) void swizzle_kernel(const float* __restrict__ W,
                                                      unsigned short* __restrict__ out,
                                                      int K, int N) {
    int idx = blockIdx.x * 256 + threadIdx.x;
    int NT = N >> 4;
    int total = (K >> 5) * NT * 64;
    if (idx >= total) return;
    int lane = idx & 63;
    int t = idx >> 6;
    int nt = t % NT;
    int ks = t / NT;
    int colIdx = nt * 16 + (lane & 15);
    int k0 = ks * 32 + ((lane >> 4) << 3);
    v8s v;
#pragma unroll
    for (int j = 0; j < 8; ++j) v[j] = (short)f2b(W[(long long)(k0 + j) * N + colIdx]);
    *(v8s*)(out + (long long)idx * 8) = v;
}

// ---------------- per-graph offsets (binary search over sorted batch) ----------------
__global__ __launch_bounds__(256) void offsets_kernel(const int* __restrict__ batch,
                                                      int* __restrict__ offs) {
    int g = blockIdx.x * 256 + threadIdx.x;
    if (g > NUM_G) return;
    // int64 vs int32 probe: last 4-byte word is high-word 0 for int64, 8191 for int32
    int stride = (batch[N_NODES - 1] == 0) ? 2 : 1;
    if (g == NUM_G) { offs[NUM_G] = N_NODES; return; }
    int lo = 0, hi = N_NODES;
    while (lo < hi) {
        int mid = (lo + hi) >> 1;
        if (batch[(long long)mid * stride] < g) lo = mid + 1; else hi = mid;
    }
    offs[g] = lo;
}

// ---------------- attention scores: s = tanh(x@W1 + b1)@W2 + b2 ----------------
// 256 thr = 4 waves; wave handles 64 nodes (4 M-tiles of 16)
__global__ __launch_bounds__(256) void attn_kernel(const float* __restrict__ x,
                                                   const bf16* __restrict__ W1sw,
                                                   const float* __restrict__ b1,
                                                   const float* __restrict__ w2,
                                                   const float* __restrict__ b2,
                                                   float* __restrict__ s_out) {
    int tid = threadIdx.x;
    int wave = tid >> 6, lane = tid & 63;
    int col = lane & 15, quad = lane >> 4;
    long long node0 = (long long)blockIdx.x * 256 + wave * 64;

    v4f acc[4][8] = {};
#pragma unroll
    for (int ks = 0; ks < 8; ++ks) {
        v8s a[4];
#pragma unroll
        for (int mt = 0; mt < 4; ++mt) {
            long long node = node0 + mt * 16 + col;
            const float4* p = (const float4*)(x + node * HDIM + ks * 32 + quad * 8);
            float4 f0 = p[0];
            float4 f1 = p[1];
            v8s a_;
            a_[0] = (short)f2b(f0.x); a_[1] = (short)f2b(f0.y);
            a_[2] = (short)f2b(f0.z); a_[3] = (short)f2b(f0.w);
            a_[4] = (short)f2b(f1.x); a_[5] = (short)f2b(f1.y);
            a_[6] = (short)f2b(f1.z); a_[7] = (short)f2b(f1.w);
            a[mt] = a_;
        }
#pragma unroll
        for (int jt = 0; jt < 8; ++jt) {
            v8s b = *(const v8s*)((const unsigned short*)W1sw + ((long long)(ks * 8 + jt) * 64 + lane) * 8);
#pragma unroll
            for (int mt = 0; mt < 4; ++mt)
                acc[mt][jt] = __builtin_amdgcn_mfma_f32_16x16x32_bf16(a[mt], b, acc[mt][jt], 0, 0, 0);
        }
    }

    float b2v = b2[0];
    float b1v[8], w2v[8];
#pragma unroll
    for (int jt = 0; jt < 8; ++jt) {
        int j = jt * 16 + col;
        b1v[jt] = b1[j];
        w2v[jt] = w2[j];
    }
#pragma unroll
    for (int mt = 0; mt < 4; ++mt) {
        float p[4] = {0.f, 0.f, 0.f, 0.f};
#pragma unroll
        for (int jt = 0; jt < 8; ++jt)
#pragma unroll
            for (int r = 0; r < 4; ++r)
                p[r] += tanhf(acc[mt][jt][r] + b1v[jt]) * w2v[jt];
#pragma unroll
        for (int r = 0; r < 4; ++r) {
#pragma unroll
            for (int off = 1; off < 16; off <<= 1) p[r] += __shfl_xor(p[r], off);
        }
        if (col == 0) {
            long long node = node0 + mt * 16;
#pragma unroll
            for (int r = 0; r < 4; ++r) s_out[node + quad * 4 + r] = p[r] + b2v;
        }
    }
}

// ---------------- block reductions ----------------
static __device__ __forceinline__ float block_sum(float v) {
    __shared__ float sm[4];
#pragma unroll
    for (int off = 32; off > 0; off >>= 1) v += __shfl_xor(v, off);
    if ((threadIdx.x & 63) == 0) sm[threadIdx.x >> 6] = v;
    __syncthreads();
    v = sm[0] + sm[1] + sm[2] + sm[3];
    __syncthreads();
    return v;
}
static __device__ __forceinline__ float block_max(float v) {
    __shared__ float sm[4];
#pragma unroll
    for (int off = 32; off > 0; off >>= 1) v = fmaxf(v, __shfl_xor(v, off));
    if ((threadIdx.x & 63) == 0) sm[threadIdx.x >> 6] = v;
    __syncthreads();
    v = fmaxf(fmaxf(sm[0], sm[1]), fmaxf(sm[2], sm[3]));
    __syncthreads();
    return v;
}

// ---------------- per-graph softmax + pooled features (bf16 out for GEMM A-side) --------
// pooled[g][0:256]=mean, [256:512]=max(0 if empty), [512:768]=softmax-weighted sum
__global__ __launch_bounds__(256) void pool_kernel(const float* __restrict__ x,
                                                   const float* __restrict__ s,
                                                   const int* __restrict__ offs,
                                                   unsigned short* __restrict__ pooled) {
    int g = blockIdx.x;
    int tid = threadIdx.x;
    int beg = offs[g], end = offs[g + 1];
    int n = end - beg;
    long long prow = (long long)g * 768;
    if (n <= 0) {
        unsigned short z = 0;
        pooled[prow + tid] = z;
        pooled[prow + 256 + tid] = z;
        pooled[prow + 512 + tid] = z;
        return;
    }
    float m = -3.0e38f;
    for (int i = beg + tid; i < end; i += 256) m = fmaxf(m, s[i]);
    m = block_max(m);
    float d = 0.f;
    for (int i = beg + tid; i < end; i += 256) d += __expf(s[i] - m);
    d = block_sum(d);
    float invd = 1.0f / d;

    float asum = 0.f, awsum = 0.f, amax = -3.0e38f;
    for (int i = beg; i < end; ++i) {
        float w = __expf(s[i] - m) * invd;
        float xv = x[(long long)i * HDIM + tid];
        asum += xv;
        awsum += w * xv;
        amax = fmaxf(amax, xv);
    }
    pooled[prow + tid]       = f2b(asum / (float)n);
    pooled[prow + 256 + tid] = f2b(amax);
    pooled[prow + 512 + tid] = f2b(awsum);
}

// ---------------- generic MFMA GEMM: C = act(A@W + b) ----------------
// A [8192,K] bf16 (row stride lda), Bsw pre-swizzled bf16 [K,N], block tile 64x64,
// wave computes 16 rows x 64 cols. mode: 0=bf16 store, 1=bf16 store + exact GELU, 2=f32 store
__global__ __launch_bounds__(256) void gemm_kernel(const unsigned short* __restrict__ A, int lda,
                                                   const unsigned short* __restrict__ Bsw,
                                                   const float* __restrict__ bias,
                                                   void* __restrict__ C, int ldc,
                                                   int K, int N, int mode) {
    int tid = threadIdx.x;
    int wave = tid >> 6, lane = tid & 63;
    int col = lane & 15, quad = lane >> 4;
    int mbase = blockIdx.x * 64 + wave * 16;
    int nbase = blockIdx.y * 64;
    int NT = N >> 4;
    int nks = K >> 5;

    v4f acc[4] = {};
    for (int ks = 0; ks < nks; ++ks) {
        v8s a = *(const v8s*)(A + (long long)(mbase + col) * lda + ks * 32 + quad * 8);
#pragma unroll
        for (int nt = 0; nt < 4; ++nt) {
            int ntg = (nbase >> 4) + nt;
            v8s b = *(const v8s*)(Bsw + ((long long)(ks * NT + ntg) * 64 + lane) * 8);
            acc[nt] = __builtin_amdgcn_mfma_f32_16x16x32_bf16(a, b, acc[nt], 0, 0, 0);
        }
    }
#pragma unroll
    for (int nt = 0; nt < 4; ++nt) {
#pragma unroll
        for (int r = 0; r < 4; ++r) {
            int row = mbase + quad * 4 + r;
            int cidx = nbase + nt * 16 + col;
            float v = acc[nt][r] + bias[cidx];
            if (mode == 1) v = 0.5f * v * (1.0f + erff(v * 0.70710678118654752f));
            if (mode == 2) ((float*)C)[(long long)row * ldc + cidx] = v;
            else ((unsigned short*)C)[(long long)row * ldc + cidx] = f2b(v);
        }
    }
}

// ---------------- LayerNorm (fp32 in/out) ----------------
__global__ __launch_bounds__(256) void ln_kernel(const float* __restrict__ pre,
                                                 const float* __restrict__ gamma,
                                                 const float* __restrict__ beta,
                                                 float* __restrict__ out) {
    int g = blockIdx.x, t = threadIdx.x;
    float v = pre[(long long)g * 256 + t];
    float mu = block_sum(v) * (1.0f / 256.0f);
    float dv = v - mu;
    float var = block_sum(dv * dv) * (1.0f / 256.0f);
    float rstd = rsqrtf(var + 1e-5f);
    out[(long long)g * 256 + t] = dv * rstd * gamma[t] + beta[t];
}

extern "C" void kernel_launch(void* const* d_in, const int* in_sizes, int n_in,
                              void* d_out, int out_size, void* d_ws, size_t ws_size,
                              hipStream_t stream) {
    const float* x      = (const float*)d_in[0];
    const int*   batch  = (const int*)d_in[1];
    const float* W_att1 = (const float*)d_in[2];
    const float* b_att1 = (const float*)d_in[3];
    const float* W_att2 = (const float*)d_in[4];
    const float* b_att2 = (const float*)d_in[5];
    const float* Wm     = (const float*)d_in[6];
    const float* bm     = (const float*)d_in[7];
    const float* Wx     = (const float*)d_in[8];
    const float* bx     = (const float*)d_in[9];
    const float* Ww     = (const float*)d_in[10];
    const float* bw     = (const float*)d_in[11];
    const float* Wc1    = (const float*)d_in[12];
    const float* bc1    = (const float*)d_in[13];
    const float* Wc2    = (const float*)d_in[14];
    const float* bc2    = (const float*)d_in[15];
    const float* gamma  = (const float*)d_in[16];
    const float* beta   = (const float*)d_in[17];
    float* out = (float*)d_out;

    char* ws = (char*)d_ws;
    size_t cur = 0;
    auto alloc = [&](size_t bytes) -> char* {
        char* p = ws + cur;
        cur += (bytes + 255) & ~(size_t)255;
        return p;
    };
    float*          s_buf    = (float*)alloc((size_t)N_NODES * 4);
    int*            offs     = (int*)  alloc((size_t)(NUM_G + 1) * 4);
    unsigned short* pooled   = (unsigned short*)alloc((size_t)NUM_G * 768 * 2);
    unsigned short* combined = (unsigned short*)alloc((size_t)NUM_G * 768 * 2);
    unsigned short* hidden   = (unsigned short*)alloc((size_t)NUM_G * 512 * 2);
    float*          pre      = (float*)alloc((size_t)NUM_G * 256 * 4);
    unsigned short* W1sw     = (unsigned short*)alloc((size_t)8  * 8  * 64 * 8 * 2);
    unsigned short* Wmsw     = (unsigned short*)alloc((size_t)8  * 16 * 64 * 8 * 2);
    unsigned short* Wxsw     = (unsigned short*)alloc((size_t)8  * 16 * 64 * 8 * 2);
    unsigned short* Wwsw     = (unsigned short*)alloc((size_t)8  * 16 * 64 * 8 * 2);
    unsigned short* Wc1sw    = (unsigned short*)alloc((size_t)24 * 32 * 64 * 8 * 2);
    unsigned short* Wc2sw    = (unsigned short*)alloc((size_t)16 * 16 * 64 * 8 * 2);

    auto swz = [&](const float* W, unsigned short* o, int K, int N) {
        int total = (K >> 5) * (N >> 4) * 64;
        swizzle_kernel<<<(total + 255) / 256, 256, 0, stream>>>(W, o, K, N);
    };
    swz(W_att1, W1sw, 256, 128);
    swz(Wm, Wmsw, 256, 256);
    swz(Wx, Wxsw, 256, 256);
    swz(Ww, Wwsw, 256, 256);
    swz(Wc1, Wc1sw, 768, 512);
    swz(Wc2, Wc2sw, 512, 256);

    offsets_kernel<<<(NUM_G + 1 + 255) / 256, 256, 0, stream>>>(batch, offs);

    attn_kernel<<<N_NODES / 256, 256, 0, stream>>>(x, (const bf16*)W1sw, b_att1, W_att2, b_att2, s_buf);

    pool_kernel<<<NUM_G, 256, 0, stream>>>(x, s_buf, offs, pooled);

    dim3 g1(NUM_G / 64, 256 / 64);
    gemm_kernel<<<g1, 256, 0, stream>>>(pooled + 0,   768, Wmsw, bm, (void*)(combined + 0),   768, 256, 256, 0);
    gemm_kernel<<<g1, 256, 0, stream>>>(pooled + 256, 768, Wxsw, bx, (void*)(combined + 256), 768, 256, 256, 0);
    gemm_kernel<<<g1, 256, 0, stream>>>(pooled + 512, 768, Wwsw, bw, (void*)(combined + 512), 768, 256, 256, 0);

    dim3 g2(NUM_G / 64, 512 / 64);
    gemm_kernel<<<g2, 256, 0, stream>>>(combined, 768, Wc1sw, bc1, (void*)hidden, 512, 768, 512, 1);

    dim3 g3(NUM_G / 64, 256 / 64);
    gemm_kernel<<<g3, 256, 0, stream>>>(hidden, 512, Wc2sw, bc2, (void*)pre, 256, 512, 256, 2);

    ln_kernel<<<NUM_G, 256, 0, stream>>>(pre, gamma, beta, out);
}